// Round 10
// baseline (133.025 us; speedup 1.0000x reference)
//
#include <hip/hip_runtime.h>

// CensusLoss = mean |census(pred)-census(target)| = mismatch_count / (8*48*512*512).
// R7 structure (proven best: stage -> one sync -> one compute site, 64x32 tile,
// 512 threads, RPT=4, no wave-split) + symmetry halving:
//   m(x,v) = [(p(x)>p(v)) != (t(x)>t(v))] is symmetric in (x,v) for tie-free
//   pairs, so  T = 2*S+ + C  where S+ sums the 24 half-space offsets
//   D+ = {dy>0} u {dy==0, dx>0} over all pixels, and C (shift-telescoping) is
//   supported only on pixels within 3 of an image edge:
//     C = sum_{x,d in D+} [x-d exits]*m(x,refl(x-d)) - [x+d exits]*m(x,refl(x+d))
//   Reflection-induced exact ties are inside C and handled exactly; accidental
//   fp ties (~1e-7 on mean) are far below the 1e-2 threshold.
// Compare work halves (96 vs 192 predicate pairs per thread-band per image).

#define BATCH 8
#define HH 512
#define WW 512
#define PLANE (HH * WW)
#define TW 64
#define TH 32
#define SCOLS 72          // staged cols: gx = tx0-4+lx (f4-aligned)
#define HROWS 38          // halo rows:  gy = ty0-3+hy
#define KPR 18            // float4 chunks per halo row (72/4)
#define PITCH 44
#define NT 512
#define LDSZ (SCOLS * PITCH)   // 3168 dwords; max index 71*44+4+37 = 3165

__device__ __forceinline__ int refl(int v, int n) {
    return v < 0 ? -v : (v >= n ? 2 * n - 2 - v : v);
}
__device__ __forceinline__ int cbase(int lx) {      // swizzled column base
    return lx * PITCH + (((lx >> 2) & 7) << 2);     // stays 0 mod 4 -> 16B cols
}

// Load 10 consecutive column floats (16B-aligned) into registers.
__device__ __forceinline__ void load_col10(const float* col, float (&w)[10]) {
    const float4 a = *(const float4*)(col);
    const float4 b = *(const float4*)(col + 4);
    const float2 d = *(const float2*)(col + 8);
    w[0] = a.x; w[1] = a.y; w[2] = a.z; w[3] = a.w;
    w[4] = b.x; w[5] = b.y; w[6] = b.z; w[7] = b.w;
    w[8] = d.x; w[9] = d.y;
}
// Rows pr0+4..pr0+9 only (dx<0 columns need just dy=1..3).
__device__ __forceinline__ void load_col6hi(const float* col, float (&w)[10]) {
    const float4 b = *(const float4*)(col + 4);
    const float2 d = *(const float2*)(col + 8);
    w[4] = b.x; w[5] = b.y; w[6] = b.z; w[7] = b.w;
    w[8] = d.x; w[9] = d.y;
}

__global__ __launch_bounds__(NT, 8)
void census_fused(const float* __restrict__ pred,
                  const float* __restrict__ target,
                  float* __restrict__ out) {
    __shared__ __align__(16) float sP[LDSZ];
    __shared__ __align__(16) float sT[LDSZ];

    const int b   = blockIdx.z;
    const int ty0 = blockIdx.y * TH;
    const int tx0 = blockIdx.x * TW;
    const float* __restrict__ pb = pred   + (size_t)b * 3 * PLANE;
    const float* __restrict__ tb = target + (size_t)b * 3 * PLANE;
    const bool fastx = (blockIdx.x >= 1 && blockIdx.x <= 6);

    // ---- stage full 72x38 halo (R7 flow, unchanged) ----
    if (fastx) {
        for (int idx = threadIdx.x; idx < HROWS * KPR; idx += NT) {
            const int hy = idx / KPR;
            const int k  = idx - hy * KPR;
            const int gy  = refl(ty0 + hy - 3, HH);
            const int off = gy * WW + tx0 - 4 + 4 * k;        // 16B-aligned
            const float4 pr = *(const float4*)(pb + off);
            const float4 pg = *(const float4*)(pb + off + PLANE);
            const float4 pc = *(const float4*)(pb + off + 2 * PLANE);
            const float4 tr = *(const float4*)(tb + off);
            const float4 tg = *(const float4*)(tb + off + PLANE);
            const float4 tc = *(const float4*)(tb + off + 2 * PLANE);
            const int lx = 4 * k;
            sP[cbase(lx + 0) + hy] = 0.299f * pr.x + 0.587f * pg.x + 0.114f * pc.x;
            sP[cbase(lx + 1) + hy] = 0.299f * pr.y + 0.587f * pg.y + 0.114f * pc.y;
            sP[cbase(lx + 2) + hy] = 0.299f * pr.z + 0.587f * pg.z + 0.114f * pc.z;
            sP[cbase(lx + 3) + hy] = 0.299f * pr.w + 0.587f * pg.w + 0.114f * pc.w;
            sT[cbase(lx + 0) + hy] = 0.299f * tr.x + 0.587f * tg.x + 0.114f * tc.x;
            sT[cbase(lx + 1) + hy] = 0.299f * tr.y + 0.587f * tg.y + 0.114f * tc.y;
            sT[cbase(lx + 2) + hy] = 0.299f * tr.z + 0.587f * tg.z + 0.114f * tc.z;
            sT[cbase(lx + 3) + hy] = 0.299f * tr.w + 0.587f * tg.w + 0.114f * tc.w;
        }
    } else {
        for (int idx = threadIdx.x; idx < HROWS * SCOLS; idx += NT) {
            const int hy = idx / SCOLS;
            const int lx = idx - hy * SCOLS;
            const int gy  = refl(ty0 + hy - 3, HH);
            const int gx  = refl(tx0 + lx - 4, WW);
            const int off = gy * WW + gx;
            sP[cbase(lx) + hy] = 0.299f * pb[off] + 0.587f * pb[off + PLANE] + 0.114f * pb[off + 2 * PLANE];
            sT[cbase(lx) + hy] = 0.299f * tb[off] + 0.587f * tb[off + PLANE] + 0.114f * tb[off + 2 * PLANE];
        }
    }
    __syncthreads();

    const int wv  = threadIdx.x >> 6;   // wave == 4-row band
    const int c   = threadIdx.x & 63;   // pixel column in tile
    const int pr0 = wv * 4;             // first pixel row (0,4,..,28); pr0 % 4 == 0

    // ---- S+ over D+ = {(0,1..3)} u {(1..3, -3..3)} : 24 offsets ----
    // Pixel (tx0+c, ty0+pr0+p), p=0..3: center at col c+4, halo row pr0+3+p.
    float wP[10], wT[10], cP[4], cT[4];
    int cnt = 0;
    load_col10(&sP[cbase(c + 4) + pr0], wP);        // dx = 0 column (holds centers)
    load_col10(&sT[cbase(c + 4) + pr0], wT);
    #pragma unroll
    for (int p = 0; p < 4; ++p) { cP[p] = wP[3 + p]; cT[p] = wT[3 + p]; }
    #pragma unroll
    for (int p = 0; p < 4; ++p) {                   // dx=0, dy=1..3
        #pragma unroll
        for (int dy = 1; dy <= 3; ++dy)
            cnt += ((cP[p] > wP[3 + p + dy]) != (cT[p] > wT[3 + p + dy])) ? 1 : 0;
    }
    #pragma unroll
    for (int t = 0; t < 3; ++t) {                   // dx=-3..-1: dy=1..3 only
        const int lx = c + 1 + t;
        load_col6hi(&sP[cbase(lx) + pr0], wP);
        load_col6hi(&sT[cbase(lx) + pr0], wT);
        #pragma unroll
        for (int p = 0; p < 4; ++p) {
            #pragma unroll
            for (int dy = 1; dy <= 3; ++dy)
                cnt += ((cP[p] > wP[3 + p + dy]) != (cT[p] > wT[3 + p + dy])) ? 1 : 0;
        }
    }
    #pragma unroll
    for (int t = 0; t < 3; ++t) {                   // dx=1..3: dy=0..3
        const int lx = c + 5 + t;
        load_col10(&sP[cbase(lx) + pr0], wP);
        load_col10(&sT[cbase(lx) + pr0], wT);
        #pragma unroll
        for (int p = 0; p < 4; ++p) {
            #pragma unroll
            for (int dy = 0; dy <= 3; ++dy)
                cnt += ((cP[p] > wP[3 + p + dy]) != (cT[p] > wT[3 + p + dy])) ? 1 : 0;
        }
    }
    cnt *= 2;                                       // T = 2*S+ + C

    // ---- border correction C (only tiles touching an image edge) ----
    if (tx0 == 0 || tx0 + TW == WW || ty0 == 0 || ty0 + TH == HH) {
        const int gx = tx0 + c;
        #pragma unroll 1
        for (int p = 0; p < 4; ++p) {
            const int gy = ty0 + pr0 + p;
            if (gx >= 3 && gx <= WW - 4 && gy >= 3 && gy <= HH - 4) continue;
            const float cp = sP[cbase(c + 4) + pr0 + 3 + p];
            const float ct = sT[cbase(c + 4) + pr0 + 3 + p];
            #pragma unroll 1
            for (int k = 0; k < 24; ++k) {          // decode D+ arithmetically
                int dy, dx;
                if (k < 3) { dy = 0; dx = k + 1; }
                else { const int j = k - 3; dy = 1 + j / 7; dx = (j % 7) - 3; }
                // minus-direction: x - d exits image -> += m(x, refl(x-d))
                if ((unsigned)(gy - dy) > (unsigned)(HH - 1) ||
                    (unsigned)(gx - dx) > (unsigned)(WW - 1)) {
                    const float np = sP[cbase(c + 4 - dx) + pr0 + 3 + p - dy];
                    const float nt = sT[cbase(c + 4 - dx) + pr0 + 3 + p - dy];
                    cnt += ((cp > np) != (ct > nt)) ? 1 : 0;
                }
                // plus-direction: x + d exits image -> -= m(x, refl(x+d))
                if ((unsigned)(gy + dy) > (unsigned)(HH - 1) ||
                    (unsigned)(gx + dx) > (unsigned)(WW - 1)) {
                    const float np = sP[cbase(c + 4 + dx) + pr0 + 3 + p + dy];
                    const float nt = sT[cbase(c + 4 + dx) + pr0 + 3 + p + dy];
                    cnt -= ((cp > np) != (ct > nt)) ? 1 : 0;
                }
            }
        }
    }

    // Reduce: 64-lane shuffle, cross-wave LDS, one atomic per block.
    #pragma unroll
    for (int o = 32; o > 0; o >>= 1) cnt += __shfl_down(cnt, o, 64);
    __shared__ int wsum[8];
    if ((threadIdx.x & 63) == 0) wsum[wv] = cnt;
    __syncthreads();
    if (threadIdx.x == 0) {
        int tot = 0;
        #pragma unroll
        for (int w = 0; w < 8; ++w) tot += wsum[w];
        // N = 8 * 48 * 512 * 512 = 100663296
        atomicAdd(out, (float)tot * (1.0f / 100663296.0f));
    }
}

extern "C" void kernel_launch(void* const* d_in, const int* in_sizes, int n_in,
                              void* d_out, int out_size, void* d_ws, size_t ws_size,
                              hipStream_t stream) {
    const float* pred   = (const float*)d_in[0];
    const float* target = (const float*)d_in[1];
    float* out = (float*)d_out;

    hipMemsetAsync(out, 0, sizeof(float), stream);   // d_out poisoned 0xAA

    dim3 grid(WW / TW, HH / TH, BATCH);              // (8, 16, 8) = 1024 blocks
    census_fused<<<grid, NT, 0, stream>>>(pred, target, out);
}

// Round 11
// 126.421 us; speedup vs baseline: 1.0522x; 1.0522x over previous
//
#include <hip/hip_runtime.h>

// CensusLoss = mean |census(pred)-census(target)| = mismatch_count / (8*48*512*512).
// R7 structure (best measured: stage -> one sync -> one uniform compute site,
// 64x32 tile, 512 threads, RPT=4) + EXACT symmetry halving (validated R9,
// absmax 0.0):  T = 2*S+ + C,
//   S+ = sum over all pixels of the 24 half-space offsets D+ = {dy=0,dx>0} u
//        {dy=1..3, dx=-3..3}, neighbor = reflected (the LDS halo already holds
//        reflected values);
//   C  = border telescoping term, supported only on pixels within 3 of an
//        image edge -> computed by a separate tiny kernel (census_border).
// R9 post-mortem: putting C's dynamically-indexed scalar loop inside the main
// kernel collapsed codegen (VGPR 16, serialized LDS waits, 61us). This round
// keeps the hot kernel branch-free and statically indexed; C runs standalone.

#define BATCH 8
#define HH 512
#define WW 512
#define PLANE (HH * WW)
#define TW 64
#define TH 32
#define SCOLS 72          // staged cols: gx = tx0-4+lx (f4-aligned)
#define HROWS 38          // halo rows:  gy = ty0-3+hy
#define KPR 18            // float4 chunks per halo row (72/4)
#define PITCH 44
#define NT 512
#define LDSZ (SCOLS * PITCH)   // 3168 dwords; max index 71*44+4+37 = 3165
#define NBORDER 6108           // 512*512 - 506*506 border pixels per image

__device__ __forceinline__ int refl(int v, int n) {
    return v < 0 ? -v : (v >= n ? 2 * n - 2 - v : v);
}
__device__ __forceinline__ int cbase(int lx) {      // swizzled column base
    return lx * PITCH + (((lx >> 2) & 7) << 2);     // stays 0 mod 4 -> 16B cols
}

// Load 10 consecutive column floats (16B-aligned) into registers.
__device__ __forceinline__ void load_col10(const float* col, float (&w)[10]) {
    const float4 a = *(const float4*)(col);
    const float4 b = *(const float4*)(col + 4);
    const float2 d = *(const float2*)(col + 8);
    w[0] = a.x; w[1] = a.y; w[2] = a.z; w[3] = a.w;
    w[4] = b.x; w[5] = b.y; w[6] = b.z; w[7] = b.w;
    w[8] = d.x; w[9] = d.y;
}

__global__ __launch_bounds__(NT, 8)
void census_fused(const float* __restrict__ pred,
                  const float* __restrict__ target,
                  float* __restrict__ out) {
    __shared__ __align__(16) float sP[LDSZ];
    __shared__ __align__(16) float sT[LDSZ];

    const int b   = blockIdx.z;
    const int ty0 = blockIdx.y * TH;
    const int tx0 = blockIdx.x * TW;
    const float* __restrict__ pb = pred   + (size_t)b * 3 * PLANE;
    const float* __restrict__ tb = target + (size_t)b * 3 * PLANE;
    const bool fastx = (blockIdx.x >= 1 && blockIdx.x <= 6);

    // ---- stage full 72x38 halo (R7 flow, unchanged) ----
    if (fastx) {
        for (int idx = threadIdx.x; idx < HROWS * KPR; idx += NT) {
            const int hy = idx / KPR;
            const int k  = idx - hy * KPR;
            const int gy  = refl(ty0 + hy - 3, HH);
            const int off = gy * WW + tx0 - 4 + 4 * k;        // 16B-aligned
            const float4 pr = *(const float4*)(pb + off);
            const float4 pg = *(const float4*)(pb + off + PLANE);
            const float4 pc = *(const float4*)(pb + off + 2 * PLANE);
            const float4 tr = *(const float4*)(tb + off);
            const float4 tg = *(const float4*)(tb + off + PLANE);
            const float4 tc = *(const float4*)(tb + off + 2 * PLANE);
            const int lx = 4 * k;
            sP[cbase(lx + 0) + hy] = 0.299f * pr.x + 0.587f * pg.x + 0.114f * pc.x;
            sP[cbase(lx + 1) + hy] = 0.299f * pr.y + 0.587f * pg.y + 0.114f * pc.y;
            sP[cbase(lx + 2) + hy] = 0.299f * pr.z + 0.587f * pg.z + 0.114f * pc.z;
            sP[cbase(lx + 3) + hy] = 0.299f * pr.w + 0.587f * pg.w + 0.114f * pc.w;
            sT[cbase(lx + 0) + hy] = 0.299f * tr.x + 0.587f * tg.x + 0.114f * tc.x;
            sT[cbase(lx + 1) + hy] = 0.299f * tr.y + 0.587f * tg.y + 0.114f * tc.y;
            sT[cbase(lx + 2) + hy] = 0.299f * tr.z + 0.587f * tg.z + 0.114f * tc.z;
            sT[cbase(lx + 3) + hy] = 0.299f * tr.w + 0.587f * tg.w + 0.114f * tc.w;
        }
    } else {
        for (int idx = threadIdx.x; idx < HROWS * SCOLS; idx += NT) {
            const int hy = idx / SCOLS;
            const int lx = idx - hy * SCOLS;
            const int gy  = refl(ty0 + hy - 3, HH);
            const int gx  = refl(tx0 + lx - 4, WW);
            const int off = gy * WW + gx;
            sP[cbase(lx) + hy] = 0.299f * pb[off] + 0.587f * pb[off + PLANE] + 0.114f * pb[off + 2 * PLANE];
            sT[cbase(lx) + hy] = 0.299f * tb[off] + 0.587f * tb[off + PLANE] + 0.114f * tb[off + 2 * PLANE];
        }
    }
    __syncthreads();

    const int wv  = threadIdx.x >> 6;   // wave == 4-row band
    const int c   = threadIdx.x & 63;   // pixel column in tile
    const int pr0 = wv * 4;             // first pixel row (0,4,..,28); pr0 % 4 == 0

    // ---- S+ over D+: pixel (tx0+c, ty0+pr0+p), center at col c+4, row pr0+3+p.
    // All rows needed lie in pr0+3..pr0+9 -> col10 window covers everything.
    float wP[10], wT[10], cP[4], cT[4];
    int cnt = 0;
    load_col10(&sP[cbase(c + 4) + pr0], wP);        // dx = 0 column (holds centers)
    load_col10(&sT[cbase(c + 4) + pr0], wT);
    #pragma unroll
    for (int p = 0; p < 4; ++p) { cP[p] = wP[3 + p]; cT[p] = wT[3 + p]; }
    #pragma unroll
    for (int p = 0; p < 4; ++p) {                   // dx=0, dy=1..3
        #pragma unroll
        for (int dy = 1; dy <= 3; ++dy)
            cnt += ((cP[p] > wP[3 + p + dy]) != (cT[p] > wT[3 + p + dy])) ? 1 : 0;
    }
    #pragma unroll
    for (int t = 0; t < 3; ++t) {                   // dx=-3..-1: dy=1..3
        const int lx = c + 1 + t;
        load_col10(&sP[cbase(lx) + pr0], wP);
        load_col10(&sT[cbase(lx) + pr0], wT);
        #pragma unroll
        for (int p = 0; p < 4; ++p) {
            #pragma unroll
            for (int dy = 1; dy <= 3; ++dy)
                cnt += ((cP[p] > wP[3 + p + dy]) != (cT[p] > wT[3 + p + dy])) ? 1 : 0;
        }
    }
    #pragma unroll
    for (int t = 0; t < 3; ++t) {                   // dx=1..3: dy=0..3
        const int lx = c + 5 + t;
        load_col10(&sP[cbase(lx) + pr0], wP);
        load_col10(&sT[cbase(lx) + pr0], wT);
        #pragma unroll
        for (int p = 0; p < 4; ++p) {
            #pragma unroll
            for (int dy = 0; dy <= 3; ++dy)
                cnt += ((cP[p] > wP[3 + p + dy]) != (cT[p] > wT[3 + p + dy])) ? 1 : 0;
        }
    }
    cnt *= 2;                                       // T = 2*S+ (+C via census_border)

    // Reduce: 64-lane shuffle, cross-wave LDS, one atomic per block.
    #pragma unroll
    for (int o = 32; o > 0; o >>= 1) cnt += __shfl_down(cnt, o, 64);
    __shared__ int wsum[8];
    if ((threadIdx.x & 63) == 0) wsum[wv] = cnt;
    __syncthreads();
    if (threadIdx.x == 0) {
        int tot = 0;
        #pragma unroll
        for (int w = 0; w < 8; ++w) tot += wsum[w];
        // N = 8 * 48 * 512 * 512 = 100663296
        atomicAdd(out, (float)tot * (1.0f / 100663296.0f));
    }
}

// Border correction C, standalone: one thread per border pixel (within 3 of an
// image edge). Gray recomputed inline (same expression/file as census_fused ->
// identical fp). C = sum_{d in D+} [x-d exits]*m(x,refl(x-d))
//                                 - [x+d exits]*m(x,refl(x+d)).
__global__ __launch_bounds__(256)
void census_border(const float* __restrict__ pred,
                   const float* __restrict__ target,
                   float* __restrict__ out) {
    const int b = blockIdx.y;
    const float* __restrict__ pb = pred   + (size_t)b * 3 * PLANE;
    const float* __restrict__ tb = target + (size_t)b * 3 * PLANE;
    const int tid = blockIdx.x * 256 + threadIdx.x;
    int cnt = 0;
    if (tid < NBORDER) {
        int x, y;
        if (tid < 1536)      { y = tid >> 9; x = tid & 511; }                       // top 3 rows
        else if (tid < 3072) { const int t = tid - 1536; y = 509 + (t >> 9); x = t & 511; } // bottom 3
        else if (tid < 4590) { const int t = tid - 3072; x = t / 506; y = 3 + (t - 506 * (t / 506)); } // left 3 cols
        else                 { const int t = tid - 4590; x = 509 + t / 506; y = 3 + (t - 506 * (t / 506)); } // right 3
        auto gray = [&](const float* img, int xx, int yy) -> float {
            const int o = yy * WW + xx;
            return 0.299f * img[o] + 0.587f * img[o + PLANE] + 0.114f * img[o + 2 * PLANE];
        };
        const float cp = gray(pb, x, y), ct = gray(tb, x, y);
        #pragma unroll
        for (int dy = 0; dy <= 3; ++dy) {
            #pragma unroll
            for (int dx = -3; dx <= 3; ++dx) {
                if (dy == 0 && dx <= 0) continue;   // D+ only
                {   // minus direction: x - d exits -> += m(x, refl(x-d))
                    const int xm = x - dx, ym = y - dy;
                    if ((unsigned)xm >= WW || (unsigned)ym >= HH) {
                        const int nx = refl(xm, WW), ny = refl(ym, HH);
                        const float np = gray(pb, nx, ny), nt = gray(tb, nx, ny);
                        cnt += ((cp > np) != (ct > nt)) ? 1 : 0;
                    }
                }
                {   // plus direction: x + d exits -> -= m(x, refl(x+d))
                    const int xp = x + dx, yp = y + dy;
                    if ((unsigned)xp >= WW || (unsigned)yp >= HH) {
                        const int nx = refl(xp, WW), ny = refl(yp, HH);
                        const float np = gray(pb, nx, ny), nt = gray(tb, nx, ny);
                        cnt -= ((cp > np) != (ct > nt)) ? 1 : 0;
                    }
                }
            }
        }
    }
    #pragma unroll
    for (int o = 32; o > 0; o >>= 1) cnt += __shfl_down(cnt, o, 64);
    __shared__ int ws[4];
    if ((threadIdx.x & 63) == 0) ws[threadIdx.x >> 6] = cnt;
    __syncthreads();
    if (threadIdx.x == 0) {
        const int tot = ws[0] + ws[1] + ws[2] + ws[3];
        atomicAdd(out, (float)tot * (1.0f / 100663296.0f));
    }
}

extern "C" void kernel_launch(void* const* d_in, const int* in_sizes, int n_in,
                              void* d_out, int out_size, void* d_ws, size_t ws_size,
                              hipStream_t stream) {
    const float* pred   = (const float*)d_in[0];
    const float* target = (const float*)d_in[1];
    float* out = (float*)d_out;

    hipMemsetAsync(out, 0, sizeof(float), stream);   // d_out poisoned 0xAA

    dim3 grid(WW / TW, HH / TH, BATCH);              // (8, 16, 8) = 1024 blocks
    census_fused<<<grid, NT, 0, stream>>>(pred, target, out);

    dim3 gb((NBORDER + 255) / 256, BATCH);           // (24, 8) = 192 blocks
    census_border<<<gb, 256, 0, stream>>>(pred, target, out);
}

// Round 12
// 107.938 us; speedup vs baseline: 1.2324x; 1.1712x over previous
//
#include <hip/hip_runtime.h>

// CensusLoss = mean |census(pred)-census(target)| = mismatch_count / (8*48*512*512).
// T = 2*S+ + C (exact; validated absmax 0.0 in R9 and R10):
//   S+ : main kernel (R10, unchanged) — R7 structure with compares halved to
//        the 24 half-space offsets D+ = {dy=0,dx>0} u {dy=1..3, dx=-3..3}.
//   C  : border telescoping term, supported on pixels within 3 of an image
//        edge. R10 computed it with scattered per-thread global reads ->
//        88MB line-waste, 52us. R11: strip-staged LDS version — 4 strips x
//        8 batches = 32 blocks, each stages its strip's full working set
//        (6x512 gray per image, coalesced) then compares against LDS.

#define BATCH 8
#define HH 512
#define WW 512
#define PLANE (HH * WW)
#define TW 64
#define TH 32
#define SCOLS 72          // staged cols: gx = tx0-4+lx (f4-aligned)
#define HROWS 38          // halo rows:  gy = ty0-3+hy
#define KPR 18            // float4 chunks per halo row (72/4)
#define PITCH 44
#define NT 512
#define LDSZ (SCOLS * PITCH)   // 3168 dwords; max index 71*44+4+37 = 3165

__device__ __forceinline__ int refl(int v, int n) {
    return v < 0 ? -v : (v >= n ? 2 * n - 2 - v : v);
}
__device__ __forceinline__ int cbase(int lx) {      // swizzled column base
    return lx * PITCH + (((lx >> 2) & 7) << 2);     // stays 0 mod 4 -> 16B cols
}

// Load 10 consecutive column floats (16B-aligned) into registers.
__device__ __forceinline__ void load_col10(const float* col, float (&w)[10]) {
    const float4 a = *(const float4*)(col);
    const float4 b = *(const float4*)(col + 4);
    const float2 d = *(const float2*)(col + 8);
    w[0] = a.x; w[1] = a.y; w[2] = a.z; w[3] = a.w;
    w[4] = b.x; w[5] = b.y; w[6] = b.z; w[7] = b.w;
    w[8] = d.x; w[9] = d.y;
}

// ---------------- main kernel: 2*S+ (R10, unchanged) ----------------
__global__ __launch_bounds__(NT, 8)
void census_fused(const float* __restrict__ pred,
                  const float* __restrict__ target,
                  float* __restrict__ out) {
    __shared__ __align__(16) float sP[LDSZ];
    __shared__ __align__(16) float sT[LDSZ];

    const int b   = blockIdx.z;
    const int ty0 = blockIdx.y * TH;
    const int tx0 = blockIdx.x * TW;
    const float* __restrict__ pb = pred   + (size_t)b * 3 * PLANE;
    const float* __restrict__ tb = target + (size_t)b * 3 * PLANE;
    const bool fastx = (blockIdx.x >= 1 && blockIdx.x <= 6);

    if (fastx) {
        for (int idx = threadIdx.x; idx < HROWS * KPR; idx += NT) {
            const int hy = idx / KPR;
            const int k  = idx - hy * KPR;
            const int gy  = refl(ty0 + hy - 3, HH);
            const int off = gy * WW + tx0 - 4 + 4 * k;        // 16B-aligned
            const float4 pr = *(const float4*)(pb + off);
            const float4 pg = *(const float4*)(pb + off + PLANE);
            const float4 pc = *(const float4*)(pb + off + 2 * PLANE);
            const float4 tr = *(const float4*)(tb + off);
            const float4 tg = *(const float4*)(tb + off + PLANE);
            const float4 tc = *(const float4*)(tb + off + 2 * PLANE);
            const int lx = 4 * k;
            sP[cbase(lx + 0) + hy] = 0.299f * pr.x + 0.587f * pg.x + 0.114f * pc.x;
            sP[cbase(lx + 1) + hy] = 0.299f * pr.y + 0.587f * pg.y + 0.114f * pc.y;
            sP[cbase(lx + 2) + hy] = 0.299f * pr.z + 0.587f * pg.z + 0.114f * pc.z;
            sP[cbase(lx + 3) + hy] = 0.299f * pr.w + 0.587f * pg.w + 0.114f * pc.w;
            sT[cbase(lx + 0) + hy] = 0.299f * tr.x + 0.587f * tg.x + 0.114f * tc.x;
            sT[cbase(lx + 1) + hy] = 0.299f * tr.y + 0.587f * tg.y + 0.114f * tc.y;
            sT[cbase(lx + 2) + hy] = 0.299f * tr.z + 0.587f * tg.z + 0.114f * tc.z;
            sT[cbase(lx + 3) + hy] = 0.299f * tr.w + 0.587f * tg.w + 0.114f * tc.w;
        }
    } else {
        for (int idx = threadIdx.x; idx < HROWS * SCOLS; idx += NT) {
            const int hy = idx / SCOLS;
            const int lx = idx - hy * SCOLS;
            const int gy  = refl(ty0 + hy - 3, HH);
            const int gx  = refl(tx0 + lx - 4, WW);
            const int off = gy * WW + gx;
            sP[cbase(lx) + hy] = 0.299f * pb[off] + 0.587f * pb[off + PLANE] + 0.114f * pb[off + 2 * PLANE];
            sT[cbase(lx) + hy] = 0.299f * tb[off] + 0.587f * tb[off + PLANE] + 0.114f * tb[off + 2 * PLANE];
        }
    }
    __syncthreads();

    const int wv  = threadIdx.x >> 6;
    const int c   = threadIdx.x & 63;
    const int pr0 = wv * 4;

    float wP[10], wT[10], cP[4], cT[4];
    int cnt = 0;
    load_col10(&sP[cbase(c + 4) + pr0], wP);
    load_col10(&sT[cbase(c + 4) + pr0], wT);
    #pragma unroll
    for (int p = 0; p < 4; ++p) { cP[p] = wP[3 + p]; cT[p] = wT[3 + p]; }
    #pragma unroll
    for (int p = 0; p < 4; ++p) {                   // dx=0, dy=1..3
        #pragma unroll
        for (int dy = 1; dy <= 3; ++dy)
            cnt += ((cP[p] > wP[3 + p + dy]) != (cT[p] > wT[3 + p + dy])) ? 1 : 0;
    }
    #pragma unroll
    for (int t = 0; t < 3; ++t) {                   // dx=-3..-1: dy=1..3
        const int lx = c + 1 + t;
        load_col10(&sP[cbase(lx) + pr0], wP);
        load_col10(&sT[cbase(lx) + pr0], wT);
        #pragma unroll
        for (int p = 0; p < 4; ++p) {
            #pragma unroll
            for (int dy = 1; dy <= 3; ++dy)
                cnt += ((cP[p] > wP[3 + p + dy]) != (cT[p] > wT[3 + p + dy])) ? 1 : 0;
        }
    }
    #pragma unroll
    for (int t = 0; t < 3; ++t) {                   // dx=1..3: dy=0..3
        const int lx = c + 5 + t;
        load_col10(&sP[cbase(lx) + pr0], wP);
        load_col10(&sT[cbase(lx) + pr0], wT);
        #pragma unroll
        for (int p = 0; p < 4; ++p) {
            #pragma unroll
            for (int dy = 0; dy <= 3; ++dy)
                cnt += ((cP[p] > wP[3 + p + dy]) != (cT[p] > wT[3 + p + dy])) ? 1 : 0;
        }
    }
    cnt *= 2;                                       // T = 2*S+ (+C via census_border)

    #pragma unroll
    for (int o = 32; o > 0; o >>= 1) cnt += __shfl_down(cnt, o, 64);
    __shared__ int wsum[8];
    if ((threadIdx.x & 63) == 0) wsum[wv] = cnt;
    __syncthreads();
    if (threadIdx.x == 0) {
        int tot = 0;
        #pragma unroll
        for (int w = 0; w < 8; ++w) tot += wsum[w];
        atomicAdd(out, (float)tot * (1.0f / 100663296.0f));  // N = 8*48*512*512
    }
}

// ---------------- border correction C, strip-staged ----------------
// C = sum_{x in border, d in D+} [x-d exits]*m(x,refl(x-d)) - [x+d exits]*m(x,refl(x+d)).
// Strips (unique pixel ownership): 0=top y:0..2 all x | 1=bottom y:509..511 all x
//                                  2=left x:0..2 y:3..508 | 3=right x:509..511 y:3..508.
// Working sets fit in one 6x512 LDS panel per image (verified per-case:
// all reflected coords stay inside the staged strip).
__global__ __launch_bounds__(512)
void census_border(const float* __restrict__ pred,
                   const float* __restrict__ target,
                   float* __restrict__ out) {
    __shared__ float gP[6 * 512];
    __shared__ float gT[6 * 512];
    const int s = blockIdx.x;               // strip
    const int b = blockIdx.y;               // batch
    const float* __restrict__ pb = pred   + (size_t)b * 3 * PLANE;
    const float* __restrict__ tb = target + (size_t)b * 3 * PLANE;
    auto gray = [&](const float* img, int x, int y) -> float {
        const int o = y * WW + x;
        return 0.299f * img[o] + 0.587f * img[o + PLANE] + 0.114f * img[o + 2 * PLANE];
    };
    int cnt = 0;
    if (s < 2) {
        // ---- top/bottom: LDS[r][x], r = y - y0, rows y0..y0+5 ----
        const int y0 = (s == 0) ? 0 : 506;
        for (int idx = threadIdx.x; idx < 6 * 512; idx += 512) {
            const int r = idx >> 9, x = idx & 511;           // coalesced in x
            gP[idx] = gray(pb, x, y0 + r);
            gT[idx] = gray(tb, x, y0 + r);
        }
        __syncthreads();
        const int py0 = (s == 0) ? 0 : 509;
        for (int i = threadIdx.x; i < 3 * 512; i += 512) {
            const int y = py0 + (i >> 9);
            const int x = i & 511;
            const float cp = gP[(y - y0) * 512 + x];
            const float ct = gT[(y - y0) * 512 + x];
            #pragma unroll
            for (int dy = 0; dy <= 3; ++dy) {
                #pragma unroll
                for (int dx = -3; dx <= 3; ++dx) {
                    if (dy == 0 && dx <= 0) continue;        // D+ only
                    const int xm = x - dx, ym = y - dy;
                    if ((unsigned)xm >= (unsigned)WW || (unsigned)ym >= (unsigned)HH) {
                        const int nx = refl(xm, WW), ny = refl(ym, HH);
                        const float np = gP[(ny - y0) * 512 + nx];
                        const float nt = gT[(ny - y0) * 512 + nx];
                        cnt += ((cp > np) != (ct > nt)) ? 1 : 0;
                    }
                    const int xp = x + dx, yp = y + dy;
                    if ((unsigned)xp >= (unsigned)WW || (unsigned)yp >= (unsigned)HH) {
                        const int nx = refl(xp, WW), ny = refl(yp, HH);
                        const float np = gP[(ny - y0) * 512 + nx];
                        const float nt = gT[(ny - y0) * 512 + nx];
                        cnt -= ((cp > np) != (ct > nt)) ? 1 : 0;
                    }
                }
            }
        }
    } else {
        // ---- left/right: LDS[y][k], k = x - x0, cols x0..x0+5; y never exits ----
        const int x0 = (s == 2) ? 0 : 506;
        for (int idx = threadIdx.x; idx < 512 * 6; idx += 512) {
            const int y = idx / 6, k = idx - 6 * y;
            gP[idx] = gray(pb, x0 + k, y);
            gT[idx] = gray(tb, x0 + k, y);
        }
        __syncthreads();
        const int px0 = (s == 2) ? 0 : 509;
        for (int i = threadIdx.x; i < 3 * 506; i += 512) {
            const int q = i / 506;
            const int x = px0 + q;
            const int y = 3 + (i - 506 * q);
            const float cp = gP[y * 6 + (x - x0)];
            const float ct = gT[y * 6 + (x - x0)];
            #pragma unroll
            for (int dy = 0; dy <= 3; ++dy) {
                #pragma unroll
                for (int dx = -3; dx <= 3; ++dx) {
                    if (dy == 0 && dx <= 0) continue;        // D+ only
                    const int xm = x - dx;                   // y-dy always in image
                    if ((unsigned)xm >= (unsigned)WW) {
                        const int nx = refl(xm, WW);
                        const float np = gP[(y - dy) * 6 + (nx - x0)];
                        const float nt = gT[(y - dy) * 6 + (nx - x0)];
                        cnt += ((cp > np) != (ct > nt)) ? 1 : 0;
                    }
                    const int xp = x + dx;
                    if ((unsigned)xp >= (unsigned)WW) {
                        const int nx = refl(xp, WW);
                        const float np = gP[(y + dy) * 6 + (nx - x0)];
                        const float nt = gT[(y + dy) * 6 + (nx - x0)];
                        cnt -= ((cp > np) != (ct > nt)) ? 1 : 0;
                    }
                }
            }
        }
    }
    #pragma unroll
    for (int o = 32; o > 0; o >>= 1) cnt += __shfl_down(cnt, o, 64);
    __shared__ int ws[8];
    if ((threadIdx.x & 63) == 0) ws[threadIdx.x >> 6] = cnt;
    __syncthreads();
    if (threadIdx.x == 0) {
        int tot = 0;
        #pragma unroll
        for (int w = 0; w < 8; ++w) tot += ws[w];
        atomicAdd(out, (float)tot * (1.0f / 100663296.0f));
    }
}

extern "C" void kernel_launch(void* const* d_in, const int* in_sizes, int n_in,
                              void* d_out, int out_size, void* d_ws, size_t ws_size,
                              hipStream_t stream) {
    const float* pred   = (const float*)d_in[0];
    const float* target = (const float*)d_in[1];
    float* out = (float*)d_out;

    hipMemsetAsync(out, 0, sizeof(float), stream);   // d_out poisoned 0xAA

    dim3 grid(WW / TW, HH / TH, BATCH);              // (8, 16, 8) = 1024 blocks
    census_fused<<<grid, NT, 0, stream>>>(pred, target, out);

    dim3 gb(4, BATCH);                               // 4 strips x 8 batches = 32 blocks
    census_border<<<gb, 512, 0, stream>>>(pred, target, out);
}

// Round 13
// 98.341 us; speedup vs baseline: 1.3527x; 1.0976x over previous
//
#include <hip/hip_runtime.h>

// CensusLoss = mean |census(pred)-census(target)| = mismatch_count / (8*48*512*512).
// R7 kernel — measured best (dur_us 98.8 total, census ~26 us) across 11
// structural variants. Fused: gray-on-the-fly into column-major LDS halo,
// b128 window reads, per-lane predicated mismatch count, one atomic per block.
//
// Session ledger (why this exact shape):
//  - 64x32 tile, 512 threads, RPT=4, stage -> ONE sync -> ONE uniform compute
//    site. Divergent wave-split pipelines (R4-R6) spill 90-170B/thread to
//    scratch (WRITE_SIZE 44-47MB) and regress 1.6-2x. Banned.
//  - stageA/computeA sandwich overlap (R8): no gain (barrier drain is
//    structural), -2.6us. Banned.
//  - Symmetry-halving T=2*S+ + C (R9-R11): exact (absmax 0.0) but never
//    faster — compute is LDS/latency-bound, not compare-bound, and the
//    border-correction kernel adds a serialized launch. Banned.
//  - float4 interior staging + cbase swizzle (this kernel) is the one staging
//    upgrade that measured as a win (R7 vs R3: 101.3 -> 98.8).
// Remaining time: ~72us harness poison fills (fixed), ~10.5us HBM floor for
// the 75MB staged fetch, ~15us compute+latency. At the structural floor.

#define BATCH 8
#define HH 512
#define WW 512
#define PLANE (HH * WW)
#define TW 64
#define TH 32
#define SCOLS 72          // staged cols: gx = tx0-4+lx (f4-aligned)
#define HROWS 38          // halo rows:  gy = ty0-3+hy
#define KPR 18            // float4 chunks per halo row (72/4)
#define PITCH 44
#define NT 512
#define LDSZ (SCOLS * PITCH)   // 3168 dwords; max index 71*44+4+37 = 3165

__device__ __forceinline__ int refl(int v, int n) {
    return v < 0 ? -v : (v >= n ? 2 * n - 2 - v : v);
}
__device__ __forceinline__ int cbase(int lx) {      // swizzled column base
    return lx * PITCH + (((lx >> 2) & 7) << 2);     // stays 0 mod 4 -> 16B cols
}

// Load 10 consecutive column floats (16B-aligned) into registers.
__device__ __forceinline__ void load_col10(const float* col, float (&w)[10]) {
    const float4 a = *(const float4*)(col);
    const float4 b = *(const float4*)(col + 4);
    const float2 d = *(const float2*)(col + 8);
    w[0] = a.x; w[1] = a.y; w[2] = a.z; w[3] = a.w;
    w[4] = b.x; w[5] = b.y; w[6] = b.z; w[7] = b.w;
    w[8] = d.x; w[9] = d.y;
}

__global__ __launch_bounds__(NT, 8)
void census_fused(const float* __restrict__ pred,
                  const float* __restrict__ target,
                  float* __restrict__ out) {
    __shared__ __align__(16) float sP[LDSZ];
    __shared__ __align__(16) float sT[LDSZ];

    const int b   = blockIdx.z;
    const int ty0 = blockIdx.y * TH;
    const int tx0 = blockIdx.x * TW;
    const float* __restrict__ pb = pred   + (size_t)b * 3 * PLANE;
    const float* __restrict__ tb = target + (size_t)b * 3 * PLANE;
    const bool fastx = (blockIdx.x >= 1 && blockIdx.x <= 6);  // gx always in range

    // ---- stage full 72x38 halo, then one barrier ----
    if (fastx) {
        for (int idx = threadIdx.x; idx < HROWS * KPR; idx += NT) {
            const int hy = idx / KPR;
            const int k  = idx - hy * KPR;
            const int gy  = refl(ty0 + hy - 3, HH);
            const int off = gy * WW + tx0 - 4 + 4 * k;        // 16B-aligned
            const float4 pr = *(const float4*)(pb + off);
            const float4 pg = *(const float4*)(pb + off + PLANE);
            const float4 pc = *(const float4*)(pb + off + 2 * PLANE);
            const float4 tr = *(const float4*)(tb + off);
            const float4 tg = *(const float4*)(tb + off + PLANE);
            const float4 tc = *(const float4*)(tb + off + 2 * PLANE);
            const int lx = 4 * k;
            sP[cbase(lx + 0) + hy] = 0.299f * pr.x + 0.587f * pg.x + 0.114f * pc.x;
            sP[cbase(lx + 1) + hy] = 0.299f * pr.y + 0.587f * pg.y + 0.114f * pc.y;
            sP[cbase(lx + 2) + hy] = 0.299f * pr.z + 0.587f * pg.z + 0.114f * pc.z;
            sP[cbase(lx + 3) + hy] = 0.299f * pr.w + 0.587f * pg.w + 0.114f * pc.w;
            sT[cbase(lx + 0) + hy] = 0.299f * tr.x + 0.587f * tg.x + 0.114f * tc.x;
            sT[cbase(lx + 1) + hy] = 0.299f * tr.y + 0.587f * tg.y + 0.114f * tc.y;
            sT[cbase(lx + 2) + hy] = 0.299f * tr.z + 0.587f * tg.z + 0.114f * tc.z;
            sT[cbase(lx + 3) + hy] = 0.299f * tr.w + 0.587f * tg.w + 0.114f * tc.w;
        }
    } else {
        for (int idx = threadIdx.x; idx < HROWS * SCOLS; idx += NT) {
            const int hy = idx / SCOLS;
            const int lx = idx - hy * SCOLS;
            const int gy  = refl(ty0 + hy - 3, HH);
            const int gx  = refl(tx0 + lx - 4, WW);
            const int off = gy * WW + gx;
            sP[cbase(lx) + hy] = 0.299f * pb[off] + 0.587f * pb[off + PLANE] + 0.114f * pb[off + 2 * PLANE];
            sT[cbase(lx) + hy] = 0.299f * tb[off] + 0.587f * tb[off + PLANE] + 0.114f * tb[off + 2 * PLANE];
        }
    }
    __syncthreads();

    const int wv  = threadIdx.x >> 6;   // wave == 4-row band
    const int c   = threadIdx.x & 63;   // pixel column in tile
    const int pr0 = wv * 4;             // first pixel row (0,4,..,28); pr0 % 4 == 0

    // Pixel (tx0+c, ty0+pr0+p), p=0..3: center at col c+4, halo row pr0+3+p;
    // window cols lx = c+1..c+7, halo rows pr0..pr0+9. Single call site.
    float wP[10], wT[10], cP[4], cT[4];
    int cnt = 0;
    load_col10(&sP[cbase(c + 4) + pr0], wP);        // dx = 0 column (holds centers)
    load_col10(&sT[cbase(c + 4) + pr0], wT);
    #pragma unroll
    for (int p = 0; p < 4; ++p) { cP[p] = wP[3 + p]; cT[p] = wT[3 + p]; }
    #pragma unroll
    for (int p = 0; p < 4; ++p) {
        #pragma unroll
        for (int dy = -3; dy <= 3; ++dy) {
            if (dy == 0) continue;                  // skip center
            cnt += ((cP[p] > wP[3 + p + dy]) != (cT[p] > wT[3 + p + dy])) ? 1 : 0;
        }
    }
    #pragma unroll
    for (int t = 0; t < 6; ++t) {
        const int lx = c + 1 + (t < 3 ? t : t + 1); // dx = -3..3, dx != 0
        load_col10(&sP[cbase(lx) + pr0], wP);
        load_col10(&sT[cbase(lx) + pr0], wT);
        #pragma unroll
        for (int p = 0; p < 4; ++p) {
            #pragma unroll
            for (int dy = -3; dy <= 3; ++dy)
                cnt += ((cP[p] > wP[3 + p + dy]) != (cT[p] > wT[3 + p + dy])) ? 1 : 0;
        }
    }

    // Reduce: 64-lane shuffle, cross-wave LDS, one atomic per block.
    #pragma unroll
    for (int o = 32; o > 0; o >>= 1) cnt += __shfl_down(cnt, o, 64);
    __shared__ int wsum[8];
    if ((threadIdx.x & 63) == 0) wsum[wv] = cnt;
    __syncthreads();
    if (threadIdx.x == 0) {
        int tot = 0;
        #pragma unroll
        for (int w = 0; w < 8; ++w) tot += wsum[w];
        // N = 8 * 48 * 512 * 512 = 100663296
        atomicAdd(out, (float)tot * (1.0f / 100663296.0f));
    }
}

extern "C" void kernel_launch(void* const* d_in, const int* in_sizes, int n_in,
                              void* d_out, int out_size, void* d_ws, size_t ws_size,
                              hipStream_t stream) {
    const float* pred   = (const float*)d_in[0];
    const float* target = (const float*)d_in[1];
    float* out = (float*)d_out;

    hipMemsetAsync(out, 0, sizeof(float), stream);   // d_out poisoned 0xAA

    dim3 grid(WW / TW, HH / TH, BATCH);              // (8, 16, 8) = 1024 blocks
    census_fused<<<grid, NT, 0, stream>>>(pred, target, out);
}